// Round 14
// baseline (4660.370 us; speedup 1.0000x reference)
//
#include <hip/hip_runtime.h>

typedef __attribute__((ext_vector_type(8))) short short8;
typedef __attribute__((ext_vector_type(4))) float f32x4;
typedef __attribute__((ext_vector_type(4))) unsigned int u32x4;

#define B_   64
#define S_   512
#define V_   1400
#define VP_  1408
#define H_   256
#define G4_  1024
#define NC_  128
#define CH_  64    // time-chunk length (8 chunks of 64 steps)

__device__ __forceinline__ unsigned short f2bf(float f) {
    unsigned u = __builtin_bit_cast(unsigned, f);
    u += 0x7FFFu + ((u >> 16) & 1u);
    return (unsigned short)(u >> 16);
}
__device__ __forceinline__ float bf2f(unsigned short h) {
    unsigned u = ((unsigned)h) << 16;
    return __builtin_bit_cast(float, u);
}
__device__ __forceinline__ float fsig(float x) {
    x = fminf(fmaxf(x, -40.f), 40.f);
    float e = __builtin_amdgcn_exp2f(x * -1.44269504f);
    return __builtin_amdgcn_rcpf(1.0f + e);
}
__device__ __forceinline__ float ftanh(float x) {
    x = fminf(fmaxf(x, -40.f), 40.f);
    float e = __builtin_amdgcn_exp2f(x * 2.88539008f);
    return 1.0f - 2.0f * __builtin_amdgcn_rcpf(e + 1.0f);
}

// ---- IC-coherent primitives (proven r2/r7/r11) ----
__device__ __forceinline__ u32x4 gload16u_sc1(const unsigned int* p) {
    u32x4 r;
    asm volatile("global_load_dwordx4 %0, %1, off sc1"
                 : "=&v"(r) : "v"((unsigned long long)p));
    return r;
}
__device__ __forceinline__ void gstore_dword_sc1(unsigned int* p, unsigned v) {
    asm volatile("global_store_dword %0, %1, off sc1"
                 :: "v"((unsigned long long)p), "v"(v));
}
__device__ __forceinline__ void gstore_short_plain(unsigned short* p, unsigned v) {
    asm volatile("global_store_short %0, %1, off"
                 :: "v"((unsigned long long)p), "v"(v));
}
// plain dword load via asm — ordered among the volatile-asm vmem stream
__device__ __forceinline__ float gloadf_plain(const float* p) {
    float r;
    asm volatile("global_load_dword %0, %1, off"
                 : "=&v"(r) : "v"((unsigned long long)p));
    return r;
}

// tagged-exchange buffers (u32 words): [parity 2][grp 8][row 16][col 256]
#define XW_WORDS_ (2 * 8 * 16 * 256)   // 65,536 words each (256 KB)

// ---------------------------------------------------------------- K0: prep
__global__ void k0_prep(const float* __restrict__ emb,
                        const float* __restrict__ Wa1, const float* __restrict__ Wa2,
                        const float* __restrict__ Wd1, const float* __restrict__ Wd2,
                        const float* __restrict__ U1,  const float* __restrict__ U2,
                        const float* __restrict__ ba1, const float* __restrict__ bu1,
                        const float* __restrict__ ba2, const float* __restrict__ bu2,
                        const float* __restrict__ Wb,
                        unsigned short* __restrict__ embT, unsigned short* __restrict__ Wg,
                        unsigned short* __restrict__ Wd,   unsigned short* __restrict__ Ub,
                        unsigned short* __restrict__ Wbb,  float* __restrict__ bg,
                        unsigned int* __restrict__ hxw, unsigned int* __restrict__ cxw) {
    int tid = blockIdx.x * blockDim.x + threadIdx.x;
    int np = gridDim.x * blockDim.x;
    for (int i = tid; i < 256 * VP_; i += np) {
        int n = i / VP_, k = i - n * VP_;
        embT[i] = (k < V_) ? f2bf(emb[k * H_ + n]) : (unsigned short)0;
    }
    for (int i = tid; i < G4_ * H_; i += np) {
        Wg[i] = f2bf(Wa1[i]); Wg[G4_ * H_ + i] = f2bf(Wa2[i]);
        Ub[i] = f2bf(U1[i]);  Ub[G4_ * H_ + i] = f2bf(U2[i]);
    }
    for (int i = tid; i < H_ * H_; i += np) {
        Wd[i] = f2bf(Wd1[i]); Wd[H_ * H_ + i] = f2bf(Wd2[i]); Wbb[i] = f2bf(Wb[i]);
    }
    for (int i = tid; i < G4_; i += np) {
        bg[i] = ba1[i] + bu1[i]; bg[G4_ + i] = ba2[i] + bu2[i];
    }
    // zero tagged-exchange buffers EVERY run (tags repeat per run; stale tags
    // from a previous bench iteration would validate spuriously).
    for (int i = tid; i < XW_WORDS_; i += np) { hxw[i] = 0; cxw[i] = 0; }
}

// ---------------------------------------------------------------- K1: embedded = inputs @ emb
__global__ __launch_bounds__(512, 2) void k1_embed(const float* __restrict__ inputs,
                                                   const unsigned short* __restrict__ embT,
                                                   unsigned short* __restrict__ embB) {
    const int tid = threadIdx.x;
    const int w = tid >> 6, ln = tid & 63, q = ln >> 4, l16 = ln & 15;
    const int mt = w >> 2, ng = (w & 3) * 4;
    const int Rbase = blockIdx.x * 32 + mt * 16;
    const float* arow = inputs + (long)(Rbase + l16) * V_;

    f32x4 acc[4];
    #pragma unroll
    for (int i = 0; i < 4; ++i) acc[i] = (f32x4){0.f, 0.f, 0.f, 0.f};

    for (int kt = 0; kt < 44; ++kt) {
        int k0 = kt * 32 + q * 8;
        short8 af;
        if (kt == 43 && q == 3) {
            #pragma unroll
            for (int j = 0; j < 8; ++j) af[j] = 0;
        } else {
            f32x4 x0 = *(const f32x4*)(arow + k0);
            f32x4 x1 = *(const f32x4*)(arow + k0 + 4);
            #pragma unroll
            for (int j = 0; j < 4; ++j) { af[j] = (short)f2bf(x0[j]); af[4 + j] = (short)f2bf(x1[j]); }
        }
        #pragma unroll
        for (int i = 0; i < 4; ++i) {
            short8 bf = *(const short8*)(embT + (long)((ng + i) * 16 + l16) * VP_ + k0);
            acc[i] = __builtin_amdgcn_mfma_f32_16x16x32_bf16(af, bf, acc[i], 0, 0, 0);
        }
    }
    #pragma unroll
    for (int i = 0; i < 4; ++i) {
        int col = (ng + i) * 16 + l16;
        #pragma unroll
        for (int j = 0; j < 4; ++j) {
            int R = Rbase + 4 * q + j;
            embB[(long)R * H_ + col] = f2bf(acc[i][j]);
        }
    }
}

// ---------------------------------------------------------------- K2: P chunk = embedded @ [U1;U2]^T + bg
// (chunk-0 prologue and no-fuse fallback)
__global__ __launch_bounds__(512, 2) void k2_pre(const unsigned short* __restrict__ embB,
                                                 const unsigned short* __restrict__ Ub,
                                                 const float* __restrict__ bg,
                                                 float* __restrict__ P, int t0) {
    const int tid = threadIdx.x;
    const int w = tid >> 6, ln = tid & 63, q = ln >> 4, l16 = ln & 15;
    const int rbase = blockIdx.x * 32;  // local row' in chunk, 0..4095

    short8 af[2][8];
    #pragma unroll
    for (int mt = 0; mt < 2; ++mt)
        #pragma unroll
        for (int kt = 0; kt < 8; ++kt) {
            int rp = rbase + mt * 16 + l16;
            int rg = t0 * 64 + rp;
            int b = rg & 63, s = rg >> 6;
            af[mt][kt] = *(const short8*)(embB + ((long)b * S_ + s) * H_ + kt * 32 + q * 8);
        }

    for (int i = 0; i < 16; ++i) {
        int nt2 = w * 16 + i;          // global gate-col tile 0..127
        int l = nt2 >> 6;
        int gcol = (nt2 & 63) * 16 + l16;   // col within lstm, 0..1023
        float bias = bg[nt2 * 16 + l16];
        short8 bf[8];
        #pragma unroll
        for (int kt = 0; kt < 8; ++kt)
            bf[kt] = *(const short8*)(Ub + (long)(nt2 * 16 + l16) * H_ + kt * 32 + q * 8);
        #pragma unroll
        for (int mt = 0; mt < 2; ++mt) {
            f32x4 acc = (f32x4){bias, bias, bias, bias};
            #pragma unroll
            for (int kt = 0; kt < 8; ++kt)
                acc = __builtin_amdgcn_mfma_f32_16x16x32_bf16(af[mt][kt], bf[kt], acc, 0, 0, 0);
            int rp0 = rbase + mt * 16;
            float* dst = P + ((long)l * (CH_ * 64) + rp0 + 4 * q) * G4_ + gcol;
            #pragma unroll
            for (int j = 0; j < 4; ++j) dst[(long)j * G4_] = acc[j];
        }
    }
}

// ---------------------------------------------------------------- K3: fused LSTM chunk + next-chunk P GEMM
// Round-19: tagged self-validating exchange, v2 (crash-risk engineered out).
//   Model (13 rounds): per-step = 4 serial IC round trips (~1800cy each:
//   drain-ack, post, poll, gather) + ~2000cy compute = 10.4Kcy = 4.33us.
//   v2 keeps only the gather RT: h/c travel as (tag<<16)|bf16 dwords in
//   parity-2 buffers; the gather IS the poll (tag==gt validates), retried.
//   De-risking vs the r12 crash: (a) PHASE-SPLIT gather — c-words validated
//   and unpacked before h-words are checked (peak live regs ~330, not ~460);
//   (b) H flight hidden under dacc MFMAs via vmcnt(16) staging (H before pv);
//   (c) retry bound 64/phase (broken protocol finishes, diagnosable);
//   (d) own-store visibility needs NO drain — stale self-read fails the tag
//   and retries; (e) no counters, no in-loop barriers.
//   Safety induction (parity-2 + monotonic tags): writer overwrites slot t&1
//   only at step t+2, whose gather waits on every peer's step-t+1 WRITES,
//   which occur after that peer's slot-(t&1) READS. Cross-chunk: tags persist
//   across dispatches; k0 zeroes buffers each run.
__global__ __launch_bounds__(256, 1) void k3_fused(const float* __restrict__ ts,
                                                   const unsigned short* __restrict__ W, // Wg || Wd
                                                   const float* __restrict__ bd1,
                                                   const float* __restrict__ bd2,
                                                   const float* __restrict__ Pcur,
                                                   unsigned short* __restrict__ out1,
                                                   unsigned short* __restrict__ out2,
                                                   float* __restrict__ cst,
                                                   unsigned int* __restrict__ hxw,
                                                   unsigned int* __restrict__ cxw,
                                                   int t0,
                                                   const unsigned short* __restrict__ embB,
                                                   const unsigned short* __restrict__ Ub,
                                                   const float* __restrict__ bg,
                                                   float* __restrict__ Pnext,
                                                   int next_t0) {
    const int tid = threadIdx.x;
    const int w = tid >> 6, ln = tid & 63, q = ln >> 4, l16 = ln & 15;
    const int bid = blockIdx.x;

    if (bid >= 32) {
        // ================= GEMM role: P(next chunk) = embB @ Ub^T + bg =======
        const int g2 = bid - 32;
        const int rbase = (g2 >> 1) * 32;
        const int hb = g2 & 1;

        short8 af[2][8];
        #pragma unroll
        for (int mt = 0; mt < 2; ++mt)
            #pragma unroll
            for (int kt = 0; kt < 8; ++kt) {
                int rp = rbase + mt * 16 + l16;
                int rg = next_t0 * 64 + rp;
                int b = rg & 63, s = rg >> 6;
                af[mt][kt] = *(const short8*)(embB + ((long)b * S_ + s) * H_ + kt * 32 + q * 8);
            }

        for (int i = 0; i < 16; ++i) {
            int nt2 = hb * 64 + w * 16 + i;
            int l = nt2 >> 6;
            int gcol = (nt2 & 63) * 16 + l16;
            float bias = bg[nt2 * 16 + l16];
            short8 bf[8];
            #pragma unroll
            for (int kt = 0; kt < 8; ++kt)
                bf[kt] = *(const short8*)(Ub + (long)(nt2 * 16 + l16) * H_ + kt * 32 + q * 8);
            #pragma unroll
            for (int mt = 0; mt < 2; ++mt) {
                f32x4 acc = (f32x4){bias, bias, bias, bias};
                #pragma unroll
                for (int kt = 0; kt < 8; ++kt)
                    acc = __builtin_amdgcn_mfma_f32_16x16x32_bf16(af[mt][kt], bf[kt], acc, 0, 0, 0);
                int rp0 = rbase + mt * 16;
                float* dst = Pnext + ((long)l * (CH_ * 64) + rp0 + 4 * q) * G4_ + gcol;
                #pragma unroll
                for (int j = 0; j < 4; ++j) dst[(long)j * G4_] = acc[j];
            }
        }
        return;
    }

    // ==================== LSTM role (blocks 0..31) ===========================
    __shared__ float ts_lds[16][CH_];    // 4 KB

    const int grp = bid & 7, cg = bid >> 3;
    const int l = grp >> 2, m = grp & 3, b0 = m * 16;
    const int hc0 = cg * 64 + w * 16;
    const int mycol = hc0 + l16;
    unsigned short* outp = l ? out2 : out1;
    const float bdv = (l ? bd2 : bd1)[mycol];

    for (int i = tid; i < 16 * CH_; i += 256) {
        int r = i >> 6, cc = i & (CH_ - 1);
        ts_lds[r][cc] = ts[(b0 + r) * S_ + t0 + cc];
    }

    // -------- register/AGPR-resident weights (loaded once per launch) --------
    short8 wg[4][8];
    short8 wd[8];
    #pragma unroll
    for (int g = 0; g < 4; ++g)
        #pragma unroll
        for (int kt = 0; kt < 8; ++kt)
            wg[g][kt] = *(const short8*)(W + ((long)(l * G4_ + g * H_ + mycol)) * H_ + kt * 32 + q * 8);
    #pragma unroll
    for (int kt = 0; kt < 8; ++kt)
        wd[kt] = *(const short8*)(W + (long)2 * G4_ * H_ + ((long)(l * H_ + mycol)) * H_ + kt * 32 + q * 8);

    float cf[4];
    if (t0 == 0) {
        cf[0] = cf[1] = cf[2] = cf[3] = 0.f;
    } else {
        #pragma unroll
        for (int j = 0; j < 4; ++j)
            cf[j] = cst[(long)grp * 4096 + (4 * q + j) * 256 + mycol];
    }
    __syncthreads();   // ts_lds ready (only barrier in the kernel)

    const float* Pbase = Pcur + ((long)l * (CH_ * 64) + b0) * G4_;

    #pragma unroll 1
    for (int t = 0; t < CH_; ++t) {
        const int gt = t0 + t;

        short8 ha[8], ca[8];
        f32x4 dacc = (f32x4){bdv, bdv, bdv, bdv};
        float pv[4][4];

        if (gt == 0) {
            #pragma unroll
            for (int kt = 0; kt < 8; ++kt) {
                #pragma unroll
                for (int jj = 0; jj < 8; ++jj) { ha[kt][jj] = 0; ca[kt][jj] = 0; }
            }
            #pragma unroll
            for (int g = 0; g < 4; ++g)
                #pragma unroll
                for (int j = 0; j < 4; ++j)
                    pv[g][j] = gloadf_plain(Pbase + ((long)t * 64 + 4 * q + j) * G4_ + g * H_ + mycol);
            asm volatile("s_waitcnt vmcnt(0)" ::: "memory");
            __builtin_amdgcn_sched_barrier(0);
        } else {
            const unsigned slotR = (unsigned)((gt - 1) & 1);
            const unsigned int* cbase = cxw + ((slotR * 8 + grp) * 16 + l16) * 256 + q * 8;
            const unsigned int* hbase = hxw + ((slotR * 8 + grp) * 16 + l16) * 256 + q * 8;
            const unsigned expw = (unsigned)gt << 16;

            // ---- phase C: tagged c-gather (the load IS the poll) ----
            {
                u32x4 cw[16];
                unsigned it = 0;
                for (;;) {
                    #pragma unroll
                    for (int kt = 0; kt < 8; ++kt) {
                        cw[2 * kt]     = gload16u_sc1(cbase + kt * 32);
                        cw[2 * kt + 1] = gload16u_sc1(cbase + kt * 32 + 4);
                    }
                    asm volatile("s_waitcnt vmcnt(0)" ::: "memory");
                    __builtin_amdgcn_sched_barrier(0);
                    unsigned bad = 0;
                    #pragma unroll
                    for (int i = 0; i < 16; ++i)
                        #pragma unroll
                        for (int j2 = 0; j2 < 4; ++j2)
                            bad |= (cw[i][j2] ^ expw) & 0xFFFF0000u;
                    if (__all(bad == 0) || ++it >= 64u) break;
                }
                #pragma unroll
                for (int kt = 0; kt < 8; ++kt) {
                    short8 cv;
                    #pragma unroll
                    for (int j2 = 0; j2 < 4; ++j2) {
                        cv[j2]     = (short)cw[2 * kt][j2];
                        cv[4 + j2] = (short)cw[2 * kt + 1][j2];
                    }
                    ca[kt] = cv;
                }
            }

            // ---- issue H loads FIRST, then pv (staged vmcnt counts) ----
            u32x4 hw[16];
            #pragma unroll
            for (int kt = 0; kt < 8; ++kt) {
                hw[2 * kt]     = gload16u_sc1(hbase + kt * 32);
                hw[2 * kt + 1] = gload16u_sc1(hbase + kt * 32 + 4);
            }
            #pragma unroll
            for (int g = 0; g < 4; ++g)
                #pragma unroll
                for (int j = 0; j < 4; ++j)
                    pv[g][j] = gloadf_plain(Pbase + ((long)t * 64 + 4 * q + j) * G4_ + g * H_ + mycol);

            // ---- dacc MFMAs on ca (hides H flight) ----
            #pragma unroll
            for (int kt = 0; kt < 8; ++kt)
                dacc = __builtin_amdgcn_mfma_f32_16x16x32_bf16(ca[kt], wd[kt], dacc, 0, 0, 0);

            asm volatile("s_waitcnt vmcnt(16)" ::: "memory");   // H arrived (pv flying)
            __builtin_amdgcn_sched_barrier(0);
            {
                unsigned bad = 0;
                #pragma unroll
                for (int i = 0; i < 16; ++i)
                    #pragma unroll
                    for (int j2 = 0; j2 < 4; ++j2)
                        bad |= (hw[i][j2] ^ expw) & 0xFFFF0000u;
                if (!__all(bad == 0)) {
                    unsigned it = 0;
                    for (;;) {
                        #pragma unroll
                        for (int kt = 0; kt < 8; ++kt) {
                            hw[2 * kt]     = gload16u_sc1(hbase + kt * 32);
                            hw[2 * kt + 1] = gload16u_sc1(hbase + kt * 32 + 4);
                        }
                        asm volatile("s_waitcnt vmcnt(0)" ::: "memory");
                        __builtin_amdgcn_sched_barrier(0);
                        unsigned bad2 = 0;
                        #pragma unroll
                        for (int i = 0; i < 16; ++i)
                            #pragma unroll
                            for (int j2 = 0; j2 < 4; ++j2)
                                bad2 |= (hw[i][j2] ^ expw) & 0xFFFF0000u;
                        if (__all(bad2 == 0) || ++it >= 64u) break;
                    }
                }
            }
            #pragma unroll
            for (int kt = 0; kt < 8; ++kt) {
                short8 hv;
                #pragma unroll
                for (int j2 = 0; j2 < 4; ++j2) {
                    hv[j2]     = (short)hw[2 * kt][j2];
                    hv[4 + j2] = (short)hw[2 * kt + 1][j2];
                }
                ha[kt] = hv;
            }
        }

        // ---- gacc MFMAs ----
        f32x4 gacc[4];
        #pragma unroll
        for (int g = 0; g < 4; ++g) {
            gacc[g] = (f32x4){0.f, 0.f, 0.f, 0.f};
            #pragma unroll
            for (int kt = 0; kt < 8; ++kt)
                gacc[g] = __builtin_amdgcn_mfma_f32_16x16x32_bf16(ha[kt], wg[g][kt], gacc[g], 0, 0, 0);
        }
        if (gt == 0) {
            #pragma unroll
            for (int kt = 0; kt < 8; ++kt)
                dacc = __builtin_amdgcn_mfma_f32_16x16x32_bf16(ca[kt], wd[kt], dacc, 0, 0, 0);
        }

        asm volatile("s_waitcnt vmcnt(0)" ::: "memory");    // pv complete
        __builtin_amdgcn_sched_barrier(0);

        // ---- elementwise + tagged stores (tag gt+1 travels WITH the data) ----
        const unsigned tagw = ((unsigned)(gt + 1)) << 16;
        const unsigned wslot = (unsigned)(gt & 1);
        unsigned int* cdst = cxw + ((wslot * 8 + grp) * 16) * 256 + mycol;
        unsigned int* hdst = hxw + ((wslot * 8 + grp) * 16) * 256 + mycol;
        #pragma unroll
        for (int j = 0; j < 4; ++j) {
            int r = 4 * q + j;
            float tv = ts_lds[r][t];
            float cs1 = ftanh(dacc[j]);
            float cadj = cf[j] + cs1 * (tv - 1.0f);
            float fg = fsig(gacc[0][j] + pv[0][j]);
            float ig = fsig(gacc[1][j] + pv[1][j]);
            float og = fsig(gacc[2][j] + pv[2][j]);
            float cg2 = fsig(gacc[3][j] + pv[3][j]);
            float cn = fg * cadj + ig * cg2;
            float hn = og * ftanh(cn);
            cf[j] = cn;
            unsigned short hb = f2bf(hn), cb = f2bf(cn);
            gstore_short_plain(outp + ((long)(b0 + r) * S_ + gt) * H_ + mycol, (unsigned)hb);
            gstore_dword_sc1(hdst + r * 256, tagw | (unsigned)hb);
            gstore_dword_sc1(cdst + r * 256, tagw | (unsigned)cb);
        }
        // no drain, no post, no barrier — the next step's tag check self-orders
    }

    // persist fp32 c for next chunk
    #pragma unroll
    for (int j = 0; j < 4; ++j)
        cst[(long)grp * 4096 + (4 * q + j) * 256 + mycol] = cf[j];
}

// ---------------------------------------------------------------- K4: fused alpha + Beta/ctx + out
__global__ __launch_bounds__(512, 2) void k4_all(const unsigned short* __restrict__ out1,
                                                 const unsigned short* __restrict__ out2,
                                                 const unsigned short* __restrict__ Wbb,
                                                 const unsigned short* __restrict__ embB,
                                                 const float* __restrict__ wa,
                                                 const float* __restrict__ Wout,
                                                 float* __restrict__ out) {
    __shared__ float sc[512];
    __shared__ float red[512];
    __shared__ float alp_l[512];
    __shared__ float cbuf[32][256];
    __shared__ float ctx_l[256];
    const int b = blockIdx.x, tid = threadIdx.x;
    const int w = tid >> 6, ln = tid & 63, q = ln >> 4, l16 = ln & 15;

    // -------- phase A: scores + softmax --------
    f32x4 wv = *(const f32x4*)(wa + ln * 4);
    for (int i = 0; i < 64; ++i) {
        int s = w * 64 + i;
        const unsigned short* row = out1 + ((long)b * S_ + s) * H_ + ln * 4;
        float d = bf2f(row[0]) * wv[0] + bf2f(row[1]) * wv[1] +
                  bf2f(row[2]) * wv[2] + bf2f(row[3]) * wv[3];
        #pragma unroll
        for (int off = 32; off; off >>= 1) d += __shfl_xor(d, off);
        if (ln == 0) sc[s] = d;
    }
    __syncthreads();
    float v = sc[tid];
    red[tid] = v;
    for (int st = 256; st; st >>= 1) {
        __syncthreads();
        if (tid < st) red[tid] = fmaxf(red[tid], red[tid + st]);
    }
    __syncthreads();
    float M = red[0];
    __syncthreads();
    float e = __builtin_amdgcn_exp2f((v - M) * 1.44269504f);
    red[tid] = e;
    for (int st = 256; st; st >>= 1) {
        __syncthreads();
        if (tid < st) red[tid] += red[tid + st];
    }
    __syncthreads();
    alp_l[tid] = e * __builtin_amdgcn_rcpf(red[0]);
    __syncthreads();

    // -------- phase B: Beta = tanh(out2 @ Wb^T); ctx accumulation --------
    float cp[16];
    #pragma unroll
    for (int nt = 0; nt < 16; ++nt) cp[nt] = 0.f;

    for (int i = 0; i < 4; ++i) {
        int mt = w * 4 + i;
        short8 af[8];
        #pragma unroll
        for (int kt = 0; kt < 8; ++kt)
            af[kt] = *(const short8*)(out2 + ((long)b * S_ + mt * 16 + l16) * H_ + kt * 32 + q * 8);
        float al[4];
        #pragma unroll
        for (int j = 0; j < 4; ++j) al[j] = alp_l[mt * 16 + 4 * q + j];
        for (int nt = 0; nt < 16; ++nt) {
            f32x4 acc = (f32x4){0.f, 0.f, 0.f, 0.f};
            #pragma unroll
            for (int kt = 0; kt < 8; ++kt) {
                short8 bf = *(const short8*)(Wbb + (long)(nt * 16 + l16) * H_ + kt * 32 + q * 8);
                acc = __builtin_amdgcn_mfma_f32_16x16x32_bf16(af[kt], bf, acc, 0, 0, 0);
            }
            #pragma unroll
            for (int j = 0; j < 4; ++j) {
                int s = mt * 16 + 4 * q + j;
                float beta = ftanh(acc[j]);
                float ev = bf2f(embB[((long)b * S_ + s) * H_ + nt * 16 + l16]);
                cp[nt] += beta * al[j] * ev;
            }
        }
    }
    #pragma unroll
    for (int nt = 0; nt < 16; ++nt) cbuf[w * 4 + q][nt * 16 + l16] = cp[nt];
    __syncthreads();
    if (tid < 256) {
        float sum = 0.f;
        for (int i = 0; i < 32; ++i) sum += cbuf[i][tid];
        ctx_l[tid] = sum;
    }
    __syncthreads();

    // -------- phase C: out = ctx @ W_out^T --------
    if (tid < NC_) {
        const float* cr = ctx_l;
        const f32x4* wr = (const f32x4*)(Wout + tid * H_);
        float acc = 0.f;
        #pragma unroll 8
        for (int i = 0; i < 64; ++i) {
            f32x4 ww = wr[i];
            acc += cr[4 * i] * ww[0] + cr[4 * i + 1] * ww[1] +
                   cr[4 * i + 2] * ww[2] + cr[4 * i + 3] * ww[3];
        }
        out[b * NC_ + tid] = acc;
    }
}

// ---------------------------------------------------------------- launch
extern "C" void kernel_launch(void* const* d_in, const int* in_sizes, int n_in,
                              void* d_out, int out_size, void* d_ws, size_t ws_size,
                              hipStream_t stream) {
    (void)in_sizes; (void)n_in; (void)out_size;
    const float* inputs = (const float*)d_in[0];
    const float* tsp    = (const float*)d_in[1];
    const float* emb    = (const float*)d_in[2];
    const float* Wa1 = (const float*)d_in[3];  const float* ba1 = (const float*)d_in[4];
    const float* U1  = (const float*)d_in[5];  const float* bu1 = (const float*)d_in[6];
    const float* Wd1 = (const float*)d_in[7];  const float* bd1 = (const float*)d_in[8];
    const float* Wa2 = (const float*)d_in[9];  const float* ba2 = (const float*)d_in[10];
    const float* U2  = (const float*)d_in[11]; const float* bu2 = (const float*)d_in[12];
    const float* Wd2 = (const float*)d_in[13]; const float* bd2 = (const float*)d_in[14];
    const float* wa  = (const float*)d_in[15];
    const float* Wb  = (const float*)d_in[16];
    const float* Wout = (const float*)d_in[17];
    float* out = (float*)d_out;

    // Workspace map (round-19: tagged exchange; alp/ctx slots dropped — k4 fused).
    char* ws = (char*)d_ws;
    unsigned short* embT = (unsigned short*)(ws + 0);            //    720,896
    unsigned short* Wg   = (unsigned short*)(ws + 720896);       //  1,048,576 (Wd must follow)
    unsigned short* Wd   = (unsigned short*)(ws + 1769472);      //    262,144
    unsigned short* Ub   = (unsigned short*)(ws + 2031616);      //  1,048,576
    unsigned short* Wbb  = (unsigned short*)(ws + 3080192);      //    131,072
    float*          bgp  = (float*)(ws + 3211264);               //      8,192
    unsigned short* embB = (unsigned short*)(ws + 3219456);      // 16,777,216
    float*          P0   = (float*)(ws + 19996672);              // 33,554,432
    unsigned short* out1 = (unsigned short*)(ws + 53551104);     // 16,777,216
    unsigned short* out2 = (unsigned short*)(ws + 70328320);     // 16,777,216
    float*          cst  = (float*)(ws + 87105536);              //    131,072
    unsigned int*   hxw  = (unsigned int*)(ws + 87236608);       //    262,144
    unsigned int*   cxw  = (unsigned int*)(ws + 87498752);       //    262,144
    float*          P1   = (float*)(ws + 87760896);              // 33,554,432 (fused path only)
    const size_t NEED_FUSED = 121315328;                         // 87,760,896 + 33,554,432
    const bool fuse = (ws_size >= NEED_FUSED);

    hipLaunchKernelGGL(k0_prep, dim3(256), dim3(256), 0, stream,
                       emb, Wa1, Wa2, Wd1, Wd2, U1, U2, ba1, bu1, ba2, bu2, Wb,
                       embT, Wg, Wd, Ub, Wbb, bgp, hxw, cxw);
    hipLaunchKernelGGL(k1_embed, dim3(1024), dim3(512), 0, stream, inputs, embT, embB);
    // prologue: P(chunk 0)
    hipLaunchKernelGGL(k2_pre, dim3(128), dim3(512), 0, stream, embB, Ub, bgp, P0, 0);

    float* Pb[2] = { P0, fuse ? P1 : P0 };
    for (int c = 0; c < 8; ++c) {
        if (fuse) {
            int ng = (c < 7) ? 256 : 0;
            hipLaunchKernelGGL(k3_fused, dim3(32 + ng), dim3(256), 0, stream,
                               tsp, Wg, bd1, bd2, Pb[c & 1], out1, out2, cst, hxw, cxw, c * CH_,
                               embB, Ub, bgp, Pb[(c + 1) & 1], (c + 1) * CH_);
        } else {
            if (c > 0)
                hipLaunchKernelGGL(k2_pre, dim3(128), dim3(512), 0, stream, embB, Ub, bgp, P0, c * CH_);
            hipLaunchKernelGGL(k3_fused, dim3(32), dim3(256), 0, stream,
                               tsp, Wg, bd1, bd2, P0, out1, out2, cst, hxw, cxw, c * CH_,
                               embB, Ub, bgp, P0, S_ /* unused: no GEMM blocks */);
        }
    }
    hipLaunchKernelGGL(k4_all, dim3(64), dim3(512), 0, stream,
                       out1, out2, Wbb, embB, wa, Wout, out);
}

// Round 15
// 2831.948 us; speedup vs baseline: 1.6456x; 1.6456x over previous
//
#include <hip/hip_runtime.h>

typedef __attribute__((ext_vector_type(8))) short short8;
typedef __attribute__((ext_vector_type(4))) float f32x4;

#define B_   64
#define S_   512
#define V_   1400
#define VP_  1408
#define H_   256
#define G4_  1024
#define NC_  128
#define CH_  64    // time-chunk length (8 chunks of 64 steps)

__device__ __forceinline__ unsigned short f2bf(float f) {
    unsigned u = __builtin_bit_cast(unsigned, f);
    u += 0x7FFFu + ((u >> 16) & 1u);
    return (unsigned short)(u >> 16);
}
__device__ __forceinline__ float bf2f(unsigned short h) {
    unsigned u = ((unsigned)h) << 16;
    return __builtin_bit_cast(float, u);
}
__device__ __forceinline__ float fsig(float x) {
    x = fminf(fmaxf(x, -40.f), 40.f);
    float e = __builtin_amdgcn_exp2f(x * -1.44269504f);
    return __builtin_amdgcn_rcpf(1.0f + e);
}
__device__ __forceinline__ float ftanh(float x) {
    x = fminf(fmaxf(x, -40.f), 40.f);
    float e = __builtin_amdgcn_exp2f(x * 2.88539008f);
    return 1.0f - 2.0f * __builtin_amdgcn_rcpf(e + 1.0f);
}

// ---- IC-coherent data primitives (proven r2/r7/r11) ----
__device__ __forceinline__ short8 gload16_sc1(const unsigned short* p) {
    short8 r;
    asm volatile("global_load_dwordx4 %0, %1, off sc1"
                 : "=&v"(r) : "v"((unsigned long long)p));
    return r;
}
__device__ __forceinline__ void gstore_short_sc1(unsigned short* p, unsigned v) {
    asm volatile("global_store_short %0, %1, off sc1"
                 :: "v"((unsigned long long)p), "v"(v));
}
// plain dword load via asm — ordered among the volatile-asm vmem stream so the
// staged vmcnt(24)/(16)/(0) counts are exact (r10/r11-validated bit-correct).
__device__ __forceinline__ float gloadf_plain(const float* p) {
    float r;
    asm volatile("global_load_dword %0, %1, off"
                 : "=&v"(r) : "v"((unsigned long long)p));
    return r;
}

// cnt zone (ints): chain cells at (chunk*8+grp)*64, 256B-spaced  [0,4096)
#define CNT_ZONE_ 4096

// ---------------------------------------------------------------- K0: prep
__global__ void k0_prep(const float* __restrict__ emb,
                        const float* __restrict__ Wa1, const float* __restrict__ Wa2,
                        const float* __restrict__ Wd1, const float* __restrict__ Wd2,
                        const float* __restrict__ U1,  const float* __restrict__ U2,
                        const float* __restrict__ ba1, const float* __restrict__ bu1,
                        const float* __restrict__ ba2, const float* __restrict__ bu2,
                        const float* __restrict__ Wb,
                        unsigned short* __restrict__ embT, unsigned short* __restrict__ Wg,
                        unsigned short* __restrict__ Wd,   unsigned short* __restrict__ Ub,
                        unsigned short* __restrict__ Wbb,  float* __restrict__ bg,
                        unsigned int* __restrict__ cnt) {
    int tid = blockIdx.x * blockDim.x + threadIdx.x;
    int np = gridDim.x * blockDim.x;
    for (int i = tid; i < 256 * VP_; i += np) {
        int n = i / VP_, k = i - n * VP_;
        embT[i] = (k < V_) ? f2bf(emb[k * H_ + n]) : (unsigned short)0;
    }
    for (int i = tid; i < G4_ * H_; i += np) {
        Wg[i] = f2bf(Wa1[i]); Wg[G4_ * H_ + i] = f2bf(Wa2[i]);
        Ub[i] = f2bf(U1[i]);  Ub[G4_ * H_ + i] = f2bf(U2[i]);
    }
    for (int i = tid; i < H_ * H_; i += np) {
        Wd[i] = f2bf(Wd1[i]); Wd[H_ * H_ + i] = f2bf(Wd2[i]); Wbb[i] = f2bf(Wb[i]);
    }
    for (int i = tid; i < G4_; i += np) {
        bg[i] = ba1[i] + bu1[i]; bg[G4_ + i] = ba2[i] + bu2[i];
    }
    for (int i = tid; i < CNT_ZONE_; i += np) cnt[i] = 0;   // chain cells, re-zeroed every run
}

// ---------------------------------------------------------------- K1: embedded = inputs @ emb
__global__ __launch_bounds__(512, 2) void k1_embed(const float* __restrict__ inputs,
                                                   const unsigned short* __restrict__ embT,
                                                   unsigned short* __restrict__ embB) {
    const int tid = threadIdx.x;
    const int w = tid >> 6, ln = tid & 63, q = ln >> 4, l16 = ln & 15;
    const int mt = w >> 2, ng = (w & 3) * 4;
    const int Rbase = blockIdx.x * 32 + mt * 16;
    const float* arow = inputs + (long)(Rbase + l16) * V_;

    f32x4 acc[4];
    #pragma unroll
    for (int i = 0; i < 4; ++i) acc[i] = (f32x4){0.f, 0.f, 0.f, 0.f};

    for (int kt = 0; kt < 44; ++kt) {
        int k0 = kt * 32 + q * 8;
        short8 af;
        if (kt == 43 && q == 3) {
            #pragma unroll
            for (int j = 0; j < 8; ++j) af[j] = 0;
        } else {
            f32x4 x0 = *(const f32x4*)(arow + k0);
            f32x4 x1 = *(const f32x4*)(arow + k0 + 4);
            #pragma unroll
            for (int j = 0; j < 4; ++j) { af[j] = (short)f2bf(x0[j]); af[4 + j] = (short)f2bf(x1[j]); }
        }
        #pragma unroll
        for (int i = 0; i < 4; ++i) {
            short8 bf = *(const short8*)(embT + (long)((ng + i) * 16 + l16) * VP_ + k0);
            acc[i] = __builtin_amdgcn_mfma_f32_16x16x32_bf16(af, bf, acc[i], 0, 0, 0);
        }
    }
    #pragma unroll
    for (int i = 0; i < 4; ++i) {
        int col = (ng + i) * 16 + l16;
        #pragma unroll
        for (int j = 0; j < 4; ++j) {
            int R = Rbase + 4 * q + j;
            embB[(long)R * H_ + col] = f2bf(acc[i][j]);
        }
    }
}

// ---------------------------------------------------------------- K2: P chunk = embedded @ [U1;U2]^T + bg
// (chunk-0 prologue and no-fuse fallback)
__global__ __launch_bounds__(512, 2) void k2_pre(const unsigned short* __restrict__ embB,
                                                 const unsigned short* __restrict__ Ub,
                                                 const float* __restrict__ bg,
                                                 float* __restrict__ P, int t0) {
    const int tid = threadIdx.x;
    const int w = tid >> 6, ln = tid & 63, q = ln >> 4, l16 = ln & 15;
    const int rbase = blockIdx.x * 32;  // local row' in chunk, 0..4095

    short8 af[2][8];
    #pragma unroll
    for (int mt = 0; mt < 2; ++mt)
        #pragma unroll
        for (int kt = 0; kt < 8; ++kt) {
            int rp = rbase + mt * 16 + l16;
            int rg = t0 * 64 + rp;
            int b = rg & 63, s = rg >> 6;
            af[mt][kt] = *(const short8*)(embB + ((long)b * S_ + s) * H_ + kt * 32 + q * 8);
        }

    for (int i = 0; i < 16; ++i) {
        int nt2 = w * 16 + i;          // global gate-col tile 0..127
        int l = nt2 >> 6;
        int gcol = (nt2 & 63) * 16 + l16;   // col within lstm, 0..1023
        float bias = bg[nt2 * 16 + l16];
        short8 bf[8];
        #pragma unroll
        for (int kt = 0; kt < 8; ++kt)
            bf[kt] = *(const short8*)(Ub + (long)(nt2 * 16 + l16) * H_ + kt * 32 + q * 8);
        #pragma unroll
        for (int mt = 0; mt < 2; ++mt) {
            f32x4 acc = (f32x4){bias, bias, bias, bias};
            #pragma unroll
            for (int kt = 0; kt < 8; ++kt)
                acc = __builtin_amdgcn_mfma_f32_16x16x32_bf16(af[mt][kt], bf[kt], acc, 0, 0, 0);
            int rp0 = rbase + mt * 16;
            float* dst = P + ((long)l * (CH_ * 64) + rp0 + 4 * q) * G4_ + gcol;
            #pragma unroll
            for (int j = 0; j < 4; ++j) dst[(long)j * G4_] = acc[j];
        }
    }
}

// ---------------------------------------------------------------- K3: fused LSTM chunk + next-chunk P GEMM
// FINAL (round-15 = round-13 verbatim, best verified 2833.9us total).
// 14 rounds established: per-step cost = ~4 serial coherent-point round trips
// (store-drain-ack, post, poll-detect, gather ~1800cy each) + ~2000cy compute
// = 4.3us/step, invariant under detection primitive (sc1-load/RMW/spec-flag/
// fence-retry/tagged-data), scope (IC/L2), topology (4-block/pair/chain), and
// transaction count. k3 = 8 x 277us is this decomposition's latency floor.
__global__ __launch_bounds__(256, 1) void k3_fused(const float* __restrict__ ts,
                                                   const unsigned short* __restrict__ W, // Wg || Wd
                                                   const float* __restrict__ bd1,
                                                   const float* __restrict__ bd2,
                                                   const float* __restrict__ Pcur,
                                                   unsigned short* __restrict__ out1,
                                                   unsigned short* __restrict__ out2,
                                                   float* __restrict__ cst,
                                                   unsigned short* __restrict__ cx,
                                                   unsigned int* __restrict__ cnt,
                                                   int t0,
                                                   const unsigned short* __restrict__ embB,
                                                   const unsigned short* __restrict__ Ub,
                                                   const float* __restrict__ bg,
                                                   float* __restrict__ Pnext,
                                                   int next_t0) {
    const int tid = threadIdx.x;
    const int w = tid >> 6, ln = tid & 63, q = ln >> 4, l16 = ln & 15;
    const int bid = blockIdx.x;

    if (bid >= 32) {
        // ================= GEMM role: P(next chunk) = embB @ Ub^T + bg =======
        const int g2 = bid - 32;
        const int rbase = (g2 >> 1) * 32;
        const int hb = g2 & 1;

        short8 af[2][8];
        #pragma unroll
        for (int mt = 0; mt < 2; ++mt)
            #pragma unroll
            for (int kt = 0; kt < 8; ++kt) {
                int rp = rbase + mt * 16 + l16;
                int rg = next_t0 * 64 + rp;
                int b = rg & 63, s = rg >> 6;
                af[mt][kt] = *(const short8*)(embB + ((long)b * S_ + s) * H_ + kt * 32 + q * 8);
            }

        for (int i = 0; i < 16; ++i) {
            int nt2 = hb * 64 + w * 16 + i;
            int l = nt2 >> 6;
            int gcol = (nt2 & 63) * 16 + l16;
            float bias = bg[nt2 * 16 + l16];
            short8 bf[8];
            #pragma unroll
            for (int kt = 0; kt < 8; ++kt)
                bf[kt] = *(const short8*)(Ub + (long)(nt2 * 16 + l16) * H_ + kt * 32 + q * 8);
            #pragma unroll
            for (int mt = 0; mt < 2; ++mt) {
                f32x4 acc = (f32x4){bias, bias, bias, bias};
                #pragma unroll
                for (int kt = 0; kt < 8; ++kt)
                    acc = __builtin_amdgcn_mfma_f32_16x16x32_bf16(af[mt][kt], bf[kt], acc, 0, 0, 0);
                int rp0 = rbase + mt * 16;
                float* dst = Pnext + ((long)l * (CH_ * 64) + rp0 + 4 * q) * G4_ + gcol;
                #pragma unroll
                for (int j = 0; j < 4; ++j) dst[(long)j * G4_] = acc[j];
            }
        }
        return;
    }

    // ==================== LSTM role (blocks 0..31) ===========================
    __shared__ float ts_lds[16][CH_];    // 4 KB

    const int chunk = t0 >> 6;
    const int grp = bid & 7, cg = bid >> 3;
    const int l = grp >> 2, m = grp & 3, b0 = m * 16;
    const int hc0 = cg * 64 + w * 16;
    const int mycol = hc0 + l16;
    unsigned int* cell = cnt + (chunk * 8 + grp) * 64;
    unsigned short* outp = l ? out2 : out1;
    const float bdv = (l ? bd2 : bd1)[mycol];

    for (int i = tid; i < 16 * CH_; i += 256) {
        int r = i >> 6, cc = i & (CH_ - 1);
        ts_lds[r][cc] = ts[(b0 + r) * S_ + t0 + cc];
    }

    // -------- register/AGPR-resident weights (loaded once per launch) --------
    short8 wg[4][8];
    short8 wd[8];
    #pragma unroll
    for (int g = 0; g < 4; ++g)
        #pragma unroll
        for (int kt = 0; kt < 8; ++kt)
            wg[g][kt] = *(const short8*)(W + ((long)(l * G4_ + g * H_ + mycol)) * H_ + kt * 32 + q * 8);
    #pragma unroll
    for (int kt = 0; kt < 8; ++kt)
        wd[kt] = *(const short8*)(W + (long)2 * G4_ * H_ + ((long)(l * H_ + mycol)) * H_ + kt * 32 + q * 8);

    float cf[4];
    if (t0 == 0) {
        cf[0] = cf[1] = cf[2] = cf[3] = 0.f;
    } else {
        #pragma unroll
        for (int j = 0; j < 4; ++j)
            cf[j] = cst[(long)grp * 4096 + (4 * q + j) * 256 + mycol];
    }
    __syncthreads();   // ts_lds ready

    const float* Pbase = Pcur + ((long)l * (CH_ * 64) + b0) * G4_;
    unsigned opaque_zero;
    asm volatile("v_mov_b32 %0, 0" : "=v"(opaque_zero));

    #pragma unroll 1
    for (int t = 0; t < CH_; ++t) {
        const int gt = t0 + t;

        // 1. rendezvous: tid0-only bounded RMW poll; block released by barrier.
        if (t) {
            if (tid == 0) {
                const unsigned tgt = 4u * (unsigned)t;
                unsigned it = 0;
                for (;;) {
                    unsigned v = __hip_atomic_fetch_add(cell, opaque_zero,
                                                        __ATOMIC_RELAXED, __HIP_MEMORY_SCOPE_AGENT);
                    if (v >= tgt || ++it >= (1u << 15)) break;
                }
            }
            __syncthreads();
        }
        __builtin_amdgcn_sched_barrier(0);

        // 2. gathers (sc1) then pv (plain, ordered) -> staged vmcnt waits
        short8 ha[8], ca[8];
        if (gt == 0) {
            #pragma unroll
            for (int kt = 0; kt < 8; ++kt) {
                #pragma unroll
                for (int jj = 0; jj < 8; ++jj) { ha[kt][jj] = 0; ca[kt][jj] = 0; }
            }
        } else {
            const unsigned short* crow = cx + ((long)(((gt - 1) & 1) * 8 + grp)) * 4096 + l16 * 256 + q * 8;
            const unsigned short* hrow = outp + ((long)(b0 + l16) * S_ + (gt - 1)) * H_ + q * 8;
            #pragma unroll
            for (int kt = 0; kt < 8; ++kt) ca[kt] = gload16_sc1(crow + kt * 32);
            #pragma unroll
            for (int kt = 0; kt < 8; ++kt) ha[kt] = gload16_sc1(hrow + kt * 32);
        }
        float pv[4][4];
        #pragma unroll
        for (int g = 0; g < 4; ++g)
            #pragma unroll
            for (int j = 0; j < 4; ++j)
                pv[g][j] = gloadf_plain(Pbase + ((long)t * 64 + 4 * q + j) * G4_ + g * H_ + mycol);

        asm volatile("s_waitcnt vmcnt(24)" ::: "memory");   // ca complete
        __builtin_amdgcn_sched_barrier(0);
        f32x4 dacc = (f32x4){bdv, bdv, bdv, bdv};
        #pragma unroll
        for (int kt = 0; kt < 8; ++kt)
            dacc = __builtin_amdgcn_mfma_f32_16x16x32_bf16(ca[kt], wd[kt], dacc, 0, 0, 0);

        asm volatile("s_waitcnt vmcnt(16)" ::: "memory");   // ha complete
        __builtin_amdgcn_sched_barrier(0);
        f32x4 gacc[4];
        #pragma unroll
        for (int g = 0; g < 4; ++g) {
            gacc[g] = (f32x4){0.f, 0.f, 0.f, 0.f};
            #pragma unroll
            for (int kt = 0; kt < 8; ++kt)
                gacc[g] = __builtin_amdgcn_mfma_f32_16x16x32_bf16(ha[kt], wg[g][kt], gacc[g], 0, 0, 0);
        }

        asm volatile("s_waitcnt vmcnt(0)" ::: "memory");    // pv complete
        __builtin_amdgcn_sched_barrier(0);

        // 3. elementwise + sc1 stores
        #pragma unroll
        for (int j = 0; j < 4; ++j) {
            int r = 4 * q + j;
            float tv = ts_lds[r][t];
            float cs1 = ftanh(dacc[j]);
            float cadj = cf[j] + cs1 * (tv - 1.0f);
            float fg = fsig(gacc[0][j] + pv[0][j]);
            float ig = fsig(gacc[1][j] + pv[1][j]);
            float og = fsig(gacc[2][j] + pv[2][j]);
            float cg2 = fsig(gacc[3][j] + pv[3][j]);
            float cn = fg * cadj + ig * cg2;
            float hn = og * ftanh(cn);
            cf[j] = cn;
            gstore_short_sc1(outp + ((long)(b0 + r) * S_ + gt) * H_ + mycol, (unsigned)f2bf(hn));
            gstore_short_sc1(cx + ((long)((gt & 1) * 8 + grp)) * 4096 + r * 256 + mycol, (unsigned)f2bf(cn));
        }

        // 4. per-wave drain -> block barrier -> ONE post
        asm volatile("s_waitcnt vmcnt(0)" ::: "memory");
        __syncthreads();
        if (tid == 0)
            (void)__hip_atomic_fetch_add(cell, 1u, __ATOMIC_RELAXED, __HIP_MEMORY_SCOPE_AGENT);
    }

    // persist fp32 c for next chunk
    #pragma unroll
    for (int j = 0; j < 4; ++j)
        cst[(long)grp * 4096 + (4 * q + j) * 256 + mycol] = cf[j];
}

// ---------------------------------------------------------------- K4: fused alpha + Beta/ctx + out
__global__ __launch_bounds__(512, 2) void k4_all(const unsigned short* __restrict__ out1,
                                                 const unsigned short* __restrict__ out2,
                                                 const unsigned short* __restrict__ Wbb,
                                                 const unsigned short* __restrict__ embB,
                                                 const float* __restrict__ wa,
                                                 const float* __restrict__ Wout,
                                                 float* __restrict__ out) {
    __shared__ float sc[512];
    __shared__ float red[512];
    __shared__ float alp_l[512];
    __shared__ float cbuf[32][256];
    __shared__ float ctx_l[256];
    const int b = blockIdx.x, tid = threadIdx.x;
    const int w = tid >> 6, ln = tid & 63, q = ln >> 4, l16 = ln & 15;

    // -------- phase A: scores + softmax --------
    f32x4 wv = *(const f32x4*)(wa + ln * 4);
    for (int i = 0; i < 64; ++i) {
        int s = w * 64 + i;
        const unsigned short* row = out1 + ((long)b * S_ + s) * H_ + ln * 4;
        float d = bf2f(row[0]) * wv[0] + bf2f(row[1]) * wv[1] +
                  bf2f(row[2]) * wv[2] + bf2f(row[3]) * wv[3];
        #pragma unroll
        for (int off = 32; off; off >>= 1) d += __shfl_xor(d, off);
        if (ln == 0) sc[s] = d;
    }
    __syncthreads();
    float v = sc[tid];
    red[tid] = v;
    for (int st = 256; st; st >>= 1) {
        __syncthreads();
        if (tid < st) red[tid] = fmaxf(red[tid], red[tid + st]);
    }
    __syncthreads();
    float M = red[0];
    __syncthreads();
    float e = __builtin_amdgcn_exp2f((v - M) * 1.44269504f);
    red[tid] = e;
    for (int st = 256; st; st >>= 1) {
        __syncthreads();
        if (tid < st) red[tid] += red[tid + st];
    }
    __syncthreads();
    alp_l[tid] = e * __builtin_amdgcn_rcpf(red[0]);
    __syncthreads();

    // -------- phase B: Beta = tanh(out2 @ Wb^T); ctx accumulation --------
    float cp[16];
    #pragma unroll
    for (int nt = 0; nt < 16; ++nt) cp[nt] = 0.f;

    for (int i = 0; i < 4; ++i) {
        int mt = w * 4 + i;
        short8 af[8];
        #pragma unroll
        for (int kt = 0; kt < 8; ++kt)
            af[kt] = *(const short8*)(out2 + ((long)b * S_ + mt * 16 + l16) * H_ + kt * 32 + q * 8);
        float al[4];
        #pragma unroll
        for (int j = 0; j < 4; ++j) al[j] = alp_l[mt * 16 + 4 * q + j];
        for (int nt = 0; nt < 16; ++nt) {
            f32x4 acc = (f32x4){0.f, 0.f, 0.f, 0.f};
            #pragma unroll
            for (int kt = 0; kt < 8; ++kt) {
                short8 bf = *(const short8*)(Wbb + (long)(nt * 16 + l16) * H_ + kt * 32 + q * 8);
                acc = __builtin_amdgcn_mfma_f32_16x16x32_bf16(af[kt], bf, acc, 0, 0, 0);
            }
            #pragma unroll
            for (int j = 0; j < 4; ++j) {
                int s = mt * 16 + 4 * q + j;
                float beta = ftanh(acc[j]);
                float ev = bf2f(embB[((long)b * S_ + s) * H_ + nt * 16 + l16]);
                cp[nt] += beta * al[j] * ev;
            }
        }
    }
    #pragma unroll
    for (int nt = 0; nt < 16; ++nt) cbuf[w * 4 + q][nt * 16 + l16] = cp[nt];
    __syncthreads();
    if (tid < 256) {
        float sum = 0.f;
        for (int i = 0; i < 32; ++i) sum += cbuf[i][tid];
        ctx_l[tid] = sum;
    }
    __syncthreads();

    // -------- phase C: out = ctx @ W_out^T --------
    if (tid < NC_) {
        const float* cr = ctx_l;
        const f32x4* wr = (const f32x4*)(Wout + tid * H_);
        float acc = 0.f;
        #pragma unroll 8
        for (int i = 0; i < 64; ++i) {
            f32x4 ww = wr[i];
            acc += cr[4 * i] * ww[0] + cr[4 * i + 1] * ww[1] +
                   cr[4 * i + 2] * ww[2] + cr[4 * i + 3] * ww[3];
        }
        out[b * NC_ + tid] = acc;
    }
}

// ---------------------------------------------------------------- launch
extern "C" void kernel_launch(void* const* d_in, const int* in_sizes, int n_in,
                              void* d_out, int out_size, void* d_ws, size_t ws_size,
                              hipStream_t stream) {
    (void)in_sizes; (void)n_in; (void)out_size;
    const float* inputs = (const float*)d_in[0];
    const float* tsp    = (const float*)d_in[1];
    const float* emb    = (const float*)d_in[2];
    const float* Wa1 = (const float*)d_in[3];  const float* ba1 = (const float*)d_in[4];
    const float* U1  = (const float*)d_in[5];  const float* bu1 = (const float*)d_in[6];
    const float* Wd1 = (const float*)d_in[7];  const float* bd1 = (const float*)d_in[8];
    const float* Wa2 = (const float*)d_in[9];  const float* ba2 = (const float*)d_in[10];
    const float* U2  = (const float*)d_in[11]; const float* bu2 = (const float*)d_in[12];
    const float* Wd2 = (const float*)d_in[13]; const float* bd2 = (const float*)d_in[14];
    const float* wa  = (const float*)d_in[15];
    const float* Wb  = (const float*)d_in[16];
    const float* Wout = (const float*)d_in[17];
    float* out = (float*)d_out;

    // Workspace map (round-15 = round-13 layout).
    char* ws = (char*)d_ws;
    unsigned short* embT = (unsigned short*)(ws + 0);            //    720,896
    unsigned short* Wg   = (unsigned short*)(ws + 720896);       //  1,048,576 (Wd must follow)
    unsigned short* Wd   = (unsigned short*)(ws + 1769472);      //    262,144
    unsigned short* Ub   = (unsigned short*)(ws + 2031616);      //  1,048,576
    unsigned short* Wbb  = (unsigned short*)(ws + 3080192);      //    131,072
    float*          bgp  = (float*)(ws + 3211264);               //      8,192
    unsigned short* embB = (unsigned short*)(ws + 3219456);      // 16,777,216
    float*          P0   = (float*)(ws + 19996672);              // 33,554,432
    unsigned short* out1 = (unsigned short*)(ws + 53551104);     // 16,777,216
    unsigned short* out2 = (unsigned short*)(ws + 70328320);     // 16,777,216
    unsigned short* cx   = (unsigned short*)(ws + 87105536);     //    131,072
    float*          cst  = (float*)(ws + 87236608);              //    131,072
    unsigned int*   cnt  = (unsigned int*)(ws + 87564288);       //    155,648
    float*          P1   = (float*)(ws + 87719936);              // 33,554,432 (fused path only)
    const size_t NEED_FUSED = 121274368;                         // 87,719,936 + 33,554,432
    const bool fuse = (ws_size >= NEED_FUSED);

    hipLaunchKernelGGL(k0_prep, dim3(256), dim3(256), 0, stream,
                       emb, Wa1, Wa2, Wd1, Wd2, U1, U2, ba1, bu1, ba2, bu2, Wb,
                       embT, Wg, Wd, Ub, Wbb, bgp, cnt);
    hipLaunchKernelGGL(k1_embed, dim3(1024), dim3(512), 0, stream, inputs, embT, embB);
    // prologue: P(chunk 0)
    hipLaunchKernelGGL(k2_pre, dim3(128), dim3(512), 0, stream, embB, Ub, bgp, P0, 0);

    float* Pb[2] = { P0, fuse ? P1 : P0 };
    for (int c = 0; c < 8; ++c) {
        if (fuse) {
            int ng = (c < 7) ? 256 : 0;
            hipLaunchKernelGGL(k3_fused, dim3(32 + ng), dim3(256), 0, stream,
                               tsp, Wg, bd1, bd2, Pb[c & 1], out1, out2, cst, cx, cnt, c * CH_,
                               embB, Ub, bgp, Pb[(c + 1) & 1], (c + 1) * CH_);
        } else {
            if (c > 0)
                hipLaunchKernelGGL(k2_pre, dim3(128), dim3(512), 0, stream, embB, Ub, bgp, P0, c * CH_);
            hipLaunchKernelGGL(k3_fused, dim3(32), dim3(256), 0, stream,
                               tsp, Wg, bd1, bd2, P0, out1, out2, cst, cx, cnt, c * CH_,
                               embB, Ub, bgp, P0, S_ /* unused: no GEMM blocks */);
        }
    }
    hipLaunchKernelGGL(k4_all, dim3(64), dim3(512), 0, stream,
                       out1, out2, Wbb, embB, wa, Wout, out);
}